// Round 15
// baseline (121.985 us; speedup 1.0000x reference)
//
#include <hip/hip_runtime.h>

#define NQ 10
#define NL 5

typedef _Float16 h2 __attribute__((ext_vector_type(2)));

__device__ __forceinline__ float fdot2(h2 a, h2 b, float c) {
    return __builtin_amdgcn_fdot2(a, b, c, false);
}
__device__ __forceinline__ h2 pkrtz(float x, float y) {
    return __builtin_bit_cast(h2, __builtin_amdgcn_cvt_pkrtz(x, y));
}
__device__ __forceinline__ unsigned h2u(h2 v) { return __builtin_bit_cast(unsigned, v); }
__device__ __forceinline__ h2 u2h(unsigned u) { return __builtin_bit_cast(h2, u); }

// ---- cross-lane xor exchange on packed u32, all VALU (verified R10-R14) ----
template <int M>
__device__ __forceinline__ unsigned lxu(unsigned u) {
    if constexpr (M == 1) {
        return (unsigned)__builtin_amdgcn_update_dpp(0, (int)u, 0xB1, 0xF, 0xF, true);
    } else if constexpr (M == 2) {
        return (unsigned)__builtin_amdgcn_update_dpp(0, (int)u, 0x4E, 0xF, 0xF, true);
    } else if constexpr (M == 4) {
        int t = __builtin_amdgcn_update_dpp(0, (int)u, 0x104, 0xF, 0x5, false);
        t     = __builtin_amdgcn_update_dpp(t, (int)u, 0x114, 0xF, 0xA, false);
        return (unsigned)t;
    } else {                       // M == 8
        return (unsigned)__builtin_amdgcn_update_dpp(0, (int)u, 0x128, 0xF, 0xF, true);
    }
}
template <int M>
__device__ __forceinline__ void swap_pair(unsigned u, unsigned& r0, unsigned& r1) {
    if constexpr (M == 16) {
        auto r = __builtin_amdgcn_permlane16_swap(u, u, false, false);
        r0 = r[0]; r1 = r[1];
    } else {
        auto r = __builtin_amdgcn_permlane32_swap(u, u, false, false);
        r0 = r[0]; r1 = r[1];
    }
}
template <int M>
__device__ __forceinline__ float lane_xor_f(float v, int lane) {
    unsigned u = __float_as_uint(v);
    if constexpr (M < 16) {
        return __uint_as_float(lxu<M>(u));
    } else {
        unsigned r0, r1;
        swap_pair<M>(u, r0, r1);
        return __uint_as_float((lane & M) ? r0 : r1);
    }
}

// U = Rz @ Ry @ Rx top row (a,b); SU(2). Stores (ar,ai,br,bi, bi,-br,ai,-ar) per gate.
__global__ void pqc_setup(const float* __restrict__ theta, float* __restrict__ gmf) {
    int g = threadIdx.x;
    if (g >= (NL + 1) * NQ) return;
    const float* th = theta + g * 3;
    float cx, sx, cy, sy, cz, sz;
    __sincosf(0.5f * th[0], &sx, &cx);
    __sincosf(0.5f * th[1], &sy, &cy);
    __sincosf(0.5f * th[2], &sz, &cz);
    float ar =  cz * cy * cx + sz * sy * sx;
    float ai =  cz * sy * sx - sz * cy * cx;
    float br = -cz * sy * cx - sz * cy * sx;
    float bi =  sz * sy * cx - cz * cy * sx;
    float* o = gmf + g * 8;
    o[0] = ar;  o[1] = ai;  o[2] = br;  o[3] = bi;
    o[4] = bi;  o[5] = -br; o[6] = ai;  o[7] = -ar;
}

// State: amp k = lane*16 + r; a[r] = packed f16 (re,im). Constants are the NEGATED
// dot2 pairs (R14's verified recipe: state flips sign each gate; pkrtz truncation
// alternates toward/away from zero; 60 gates even -> final sign +).
// C0=-(War,-Wai) C1=-(Wai,War) [w00] C2=-(Wbr,-Wbi) C3=-(Wbi,Wbr) [w01]
// C4=-(-Wbr,-Wbi) C5=-(Wbi,-Wbr) [w10] C6=-(War,Wai) C7=-(-Wai,War) [w11]
template <int P>
__device__ __forceinline__ void apply_p(h2 a[16], const unsigned c[8], int lane) {
    if constexpr (P < 4) {
        constexpr int LJ = 1 << P;
        h2 c0 = u2h(c[0]), c1 = u2h(c[1]), c2 = u2h(c[2]), c3 = u2h(c[3]);
        h2 c4 = u2h(c[4]), c5 = u2h(c[5]), c6 = u2h(c[6]), c7 = u2h(c[7]);
#pragma unroll
        for (int base = 0; base < 16; ++base) {
            if (base & LJ) continue;
            h2 a0 = a[base], a1 = a[base | LJ];
            float r0re = fdot2(c2, a1, fdot2(c0, a0, 0.f));
            float r0im = fdot2(c3, a1, fdot2(c1, a0, 0.f));
            float r1re = fdot2(c6, a1, fdot2(c4, a0, 0.f));
            float r1im = fdot2(c7, a1, fdot2(c5, a0, 0.f));
            a[base]      = pkrtz(r0re, r0im);
            a[base | LJ] = pkrtz(r1re, r1im);
        }
    } else if constexpr (P < 8) {
        constexpr int M = 1 << (P - 4);
        const int bit = (lane >> (P - 4)) & 1;
        h2 P1 = u2h(bit ? c[6] : c[0]), P2 = u2h(bit ? c[7] : c[1]);
        h2 Q1 = u2h(bit ? c[4] : c[2]), Q2 = u2h(bit ? c[5] : c[3]);
#pragma unroll
        for (int r = 0; r < 16; ++r) {
            h2 t = u2h(lxu<M>(h2u(a[r])));
            float re = fdot2(Q1, t, fdot2(P1, a[r], 0.f));
            float im = fdot2(Q2, t, fdot2(P2, a[r], 0.f));
            a[r] = pkrtz(re, im);
        }
    } else {
        constexpr int M = 1 << (P - 4);
        const bool hi = (lane & M) != 0;
        h2 A1 = u2h(hi ? c[4] : c[0]), A2 = u2h(hi ? c[5] : c[1]);
        h2 B1 = u2h(hi ? c[6] : c[2]), B2 = u2h(hi ? c[7] : c[3]);
#pragma unroll
        for (int r = 0; r < 16; ++r) {
            unsigned r0, r1;
            swap_pair<M>(h2u(a[r]), r0, r1);
            float re = fdot2(B1, u2h(r1), fdot2(A1, u2h(r0), 0.f));
            float im = fdot2(B2, u2h(r1), fdot2(A2, u2h(r0), 0.f));
            a[r] = pkrtz(re, im);
        }
    }
}

// In-register coefficient build (RNE casts for constants, as R14's passing precomp)
// then dot2 apply. W = c*V0 + s*V1, top row (War,Wai,Wbr,Wbi).
#define GATE(qq, PP)                                                           \
    {                                                                          \
        const float* g = gl + (qq) * 8;                                        \
        float c = cc[qq], s = ss[qq];                                          \
        _Float16 ar = (_Float16)(c * g[0] + s * g[4]);                         \
        _Float16 ai = (_Float16)(c * g[1] + s * g[5]);                         \
        _Float16 br = (_Float16)(c * g[2] + s * g[6]);                         \
        _Float16 bi = (_Float16)(c * g[3] + s * g[7]);                         \
        _Float16 nar = -ar, nai = -ai, nbr = -br, nbi = -bi;                   \
        unsigned C[8];                                                         \
        C[0] = h2u(h2{ nar, ai });  C[1] = h2u(h2{ nai, nar });                \
        C[2] = h2u(h2{ nbr, bi });  C[3] = h2u(h2{ nbi, nbr });                \
        C[4] = h2u(h2{ br,  bi });  C[5] = h2u(h2{ nbi, br  });                \
        C[6] = h2u(h2{ nar, nai }); C[7] = h2u(h2{ ai,  nar });                \
        apply_p<PP>(a, C, lane);                                               \
    }

__global__ void __launch_bounds__(64, 2) pqc_kernel(const float* __restrict__ x,
                                                    const float* __restrict__ lam,
                                                    const float* __restrict__ w,
                                                    const float* __restrict__ gmf,
                                                    float* __restrict__ out, int B) {
    const int lane = threadIdx.x;
    const int b = blockIdx.x;

    h2 a[16];
#pragma unroll
    for (int r = 0; r < 16; ++r) a[r] = h2{ (_Float16)0.f, (_Float16)0.f };
    if (lane == 0) a[0] = h2{ (_Float16)1.f, (_Float16)0.f };

    // CZ-ring sign-xor masks (flip both packed halves) and Z^n parity bits.
    unsigned xm[16];
    unsigned zmask = 0;
#pragma unroll
    for (int r = 0; r < 16; ++r) {
        int k = (lane << 4) | r;
        int par = (__popc(k & (k >> 1)) + ((k & (k >> 9)) & 1)) & 1;
        xm[r] = par ? 0x80008000u : 0u;
        zmask |= (unsigned)(__popc(k) & 1) << r;
    }

    float xr[NQ];
#pragma unroll
    for (int q = 0; q < NQ; ++q) xr[q] = x[b * NQ + q];

    // 6 layers; wire q hits bit 9-q. Layer 0: en=0 -> sincos(0)=(0,1) -> W=V0.
    // CZ after every layer except the last (diag(+-1) is a no-op before |amp|^2).
#pragma clang loop unroll(disable)
    for (int l = 0; l <= NL; ++l) {
        const float* gl = gmf + l * NQ * 8;
        const float* lm = lam + (l > 0 ? (l - 1) * NQ : 0);
        const float en = (l > 0) ? 0.5f : 0.0f;
        float cc[NQ], ss[NQ];
#pragma unroll
        for (int q = 0; q < NQ; ++q)
            __sincosf(en * xr[q] * lm[q], &ss[q], &cc[q]);
        GATE(0, 9) GATE(1, 8) GATE(2, 7) GATE(3, 6) GATE(4, 5)
        GATE(5, 4) GATE(6, 3) GATE(7, 2) GATE(8, 1) GATE(9, 0)
        if (l != NL) {
#pragma unroll
            for (int r = 0; r < 16; ++r) a[r] = u2h(h2u(a[r]) ^ xm[r]);
        }
    }

    // <Z^n> = sum |amp|^2 * (-1)^popcount(k)  (dot2 of sign-flipped copy with itself)
    float ez = 0.f;
#pragma unroll
    for (int r = 0; r < 16; ++r) {
        unsigned zx = ((zmask >> r) & 1u) ? 0x80008000u : 0u;
        ez = fdot2(u2h(h2u(a[r]) ^ zx), a[r], ez);
    }
    ez += lane_xor_f<1>(ez, lane);
    ez += lane_xor_f<2>(ez, lane);
    ez += lane_xor_f<4>(ez, lane);
    ez += lane_xor_f<8>(ez, lane);
    ez += lane_xor_f<16>(ez, lane);
    ez += lane_xor_f<32>(ez, lane);

    if (lane == 0) {
        float l0 = ez * w[0], l1 = ez * w[1];   // BETA = 1
        float m = fmaxf(l0, l1);
        float e0 = __expf(l0 - m), e1 = __expf(l1 - m);
        float inv = 1.f / (e0 + e1);
        out[2 * b + 0] = e0 * inv;
        out[2 * b + 1] = e1 * inv;
    }
}

extern "C" void kernel_launch(void* const* d_in, const int* in_sizes, int n_in,
                              void* d_out, int out_size, void* d_ws, size_t ws_size,
                              hipStream_t stream) {
    const float* x     = (const float*)d_in[0];
    const float* theta = (const float*)d_in[1];
    const float* lam   = (const float*)d_in[2];
    const float* w     = (const float*)d_in[3];
    float* out = (float*)d_out;
    float* gmf = (float*)d_ws;                 // 60 gates * 8 f32 = 1920 B

    const int B = in_sizes[0] / NQ;            // 2048
    hipLaunchKernelGGL(pqc_setup,  dim3(1), dim3(64), 0, stream, theta, gmf);
    hipLaunchKernelGGL(pqc_kernel, dim3(B), dim3(64), 0, stream,
                       x, lam, w, gmf, out, B);
}

// Round 16
// 96.549 us; speedup vs baseline: 1.2635x; 1.2635x over previous
//
#include <hip/hip_runtime.h>

#define NQ 10
#define NL 5

typedef _Float16 h2 __attribute__((ext_vector_type(2)));

__device__ __forceinline__ float fdot2(h2 a, h2 b, float c) {
    return __builtin_amdgcn_fdot2(a, b, c, false);
}
__device__ __forceinline__ h2 pkrtz(float x, float y) {
    return __builtin_bit_cast(h2, __builtin_amdgcn_cvt_pkrtz(x, y));
}
__device__ __forceinline__ unsigned h2u(h2 v) { return __builtin_bit_cast(unsigned, v); }
__device__ __forceinline__ h2 u2h(unsigned u) { return __builtin_bit_cast(h2, u); }
__device__ __forceinline__ unsigned pk2(_Float16 lo, _Float16 hi) { return h2u(h2{ lo, hi }); }

// ---- cross-lane xor exchange on packed u32, all VALU (verified R10-R14) ----
template <int M>
__device__ __forceinline__ unsigned lxu(unsigned u) {
    if constexpr (M == 1) {
        return (unsigned)__builtin_amdgcn_update_dpp(0, (int)u, 0xB1, 0xF, 0xF, true);
    } else if constexpr (M == 2) {
        return (unsigned)__builtin_amdgcn_update_dpp(0, (int)u, 0x4E, 0xF, 0xF, true);
    } else if constexpr (M == 4) {
        int t = __builtin_amdgcn_update_dpp(0, (int)u, 0x104, 0xF, 0x5, false);
        t     = __builtin_amdgcn_update_dpp(t, (int)u, 0x114, 0xF, 0xA, false);
        return (unsigned)t;
    } else {                       // M == 8
        return (unsigned)__builtin_amdgcn_update_dpp(0, (int)u, 0x128, 0xF, 0xF, true);
    }
}
template <int M>
__device__ __forceinline__ void swap_pair(unsigned u, unsigned& r0, unsigned& r1) {
    if constexpr (M == 16) {
        auto r = __builtin_amdgcn_permlane16_swap(u, u, false, false);
        r0 = r[0]; r1 = r[1];
    } else {
        auto r = __builtin_amdgcn_permlane32_swap(u, u, false, false);
        r0 = r[0]; r1 = r[1];
    }
}
template <int M>
__device__ __forceinline__ float lane_xor_f(float v, int lane) {
    unsigned u = __float_as_uint(v);
    if constexpr (M < 16) {
        return __uint_as_float(lxu<M>(u));
    } else {
        unsigned r0, r1;
        swap_pair<M>(u, r0, r1);
        return __uint_as_float((lane & M) ? r0 : r1);
    }
}

// U = Rz @ Ry @ Rx top row (a,b); SU(2). Stores (ar,ai,br,bi, bi,-br,ai,-ar) per gate.
__global__ void pqc_setup(const float* __restrict__ theta, float* __restrict__ gmf) {
    int g = threadIdx.x;
    if (g >= (NL + 1) * NQ) return;
    const float* th = theta + g * 3;
    float cx, sx, cy, sy, cz, sz;
    __sincosf(0.5f * th[0], &sx, &cx);
    __sincosf(0.5f * th[1], &sy, &cy);
    __sincosf(0.5f * th[2], &sz, &cz);
    float ar =  cz * cy * cx + sz * sy * sx;
    float ai =  cz * sy * sx - sz * cy * cx;
    float br = -cz * sy * cx - sz * cy * sx;
    float bi =  sz * sy * cx - cz * cy * sx;
    float* o = gmf + g * 8;
    o[0] = ar;  o[1] = ai;  o[2] = br;  o[3] = bi;
    o[4] = bi;  o[5] = -br; o[6] = ai;  o[7] = -ar;
}

// State: amp k = lane*16 + r; a[r] = packed f16 (re,im). Coefficients are the NEGATED
// dot2 pairs (R14's verified recipe: state flips sign each gate; pkrtz truncation
// alternates toward/away from zero; 60 gates even -> final sign +). Passed as 8
// SCALARS — no local array, nothing address-taken, no LDS demotion (R15's bug).
// c0=-(War,-Wai) c1=-(Wai,War) [w00] c2=-(Wbr,-Wbi) c3=-(Wbi,Wbr) [w01]
// c4=-(-Wbr,-Wbi) c5=-(Wbi,-Wbr) [w10] c6=-(War,Wai) c7=-(-Wai,War) [w11]
template <int P>
__device__ __forceinline__ void apply_p(h2 a[16],
                                        unsigned c0, unsigned c1, unsigned c2, unsigned c3,
                                        unsigned c4, unsigned c5, unsigned c6, unsigned c7,
                                        int lane) {
    if constexpr (P < 4) {
        constexpr int LJ = 1 << P;
        h2 k0 = u2h(c0), k1 = u2h(c1), k2 = u2h(c2), k3 = u2h(c3);
        h2 k4 = u2h(c4), k5 = u2h(c5), k6 = u2h(c6), k7 = u2h(c7);
#pragma unroll
        for (int base = 0; base < 16; ++base) {
            if (base & LJ) continue;
            h2 a0 = a[base], a1 = a[base | LJ];
            float r0re = fdot2(k2, a1, fdot2(k0, a0, 0.f));
            float r0im = fdot2(k3, a1, fdot2(k1, a0, 0.f));
            float r1re = fdot2(k6, a1, fdot2(k4, a0, 0.f));
            float r1im = fdot2(k7, a1, fdot2(k5, a0, 0.f));
            a[base]      = pkrtz(r0re, r0im);
            a[base | LJ] = pkrtz(r1re, r1im);
        }
    } else if constexpr (P < 8) {
        constexpr int M = 1 << (P - 4);
        const int bit = (lane >> (P - 4)) & 1;
        h2 P1 = u2h(bit ? c6 : c0), P2 = u2h(bit ? c7 : c1);
        h2 Q1 = u2h(bit ? c4 : c2), Q2 = u2h(bit ? c5 : c3);
#pragma unroll
        for (int r = 0; r < 16; ++r) {
            h2 t = u2h(lxu<M>(h2u(a[r])));
            float re = fdot2(Q1, t, fdot2(P1, a[r], 0.f));
            float im = fdot2(Q2, t, fdot2(P2, a[r], 0.f));
            a[r] = pkrtz(re, im);
        }
    } else {
        constexpr int M = 1 << (P - 4);
        const bool hi = (lane & M) != 0;
        h2 A1 = u2h(hi ? c4 : c0), A2 = u2h(hi ? c5 : c1);
        h2 B1 = u2h(hi ? c6 : c2), B2 = u2h(hi ? c7 : c3);
#pragma unroll
        for (int r = 0; r < 16; ++r) {
            unsigned r0, r1;
            swap_pair<M>(h2u(a[r]), r0, r1);
            float re = fdot2(B1, u2h(r1), fdot2(A1, u2h(r0), 0.f));
            float im = fdot2(B2, u2h(r1), fdot2(A2, u2h(r0), 0.f));
            a[r] = pkrtz(re, im);
        }
    }
}

// In-register coefficient build (RNE casts, R14's passing recipe) -> 8 scalar u32.
#define GATE(qq, PP)                                                           \
    {                                                                          \
        const float* g = gl + (qq) * 8;                                        \
        float c = cc[qq], s = ss[qq];                                          \
        _Float16 ar = (_Float16)(c * g[0] + s * g[4]);                         \
        _Float16 ai = (_Float16)(c * g[1] + s * g[5]);                         \
        _Float16 br = (_Float16)(c * g[2] + s * g[6]);                         \
        _Float16 bi = (_Float16)(c * g[3] + s * g[7]);                         \
        _Float16 nar = -ar, nai = -ai, nbr = -br, nbi = -bi;                   \
        apply_p<PP>(a,                                                         \
            pk2(nar, ai),  pk2(nai, nar), pk2(nbr, bi),  pk2(nbi, nbr),        \
            pk2(br,  bi),  pk2(nbi, br),  pk2(nar, nai), pk2(ai,  nar), lane); \
    }

__global__ void __launch_bounds__(64, 2) pqc_kernel(const float* __restrict__ x,
                                                    const float* __restrict__ lam,
                                                    const float* __restrict__ w,
                                                    const float* __restrict__ gmf,
                                                    float* __restrict__ out, int B) {
    const int lane = threadIdx.x;
    const int b = blockIdx.x;

    h2 a[16];
#pragma unroll
    for (int r = 0; r < 16; ++r) a[r] = h2{ (_Float16)0.f, (_Float16)0.f };
    if (lane == 0) a[0] = h2{ (_Float16)1.f, (_Float16)0.f };

    // CZ-ring sign-xor masks (flip both packed halves) and Z^n parity bits.
    unsigned xm[16];
    unsigned zmask = 0;
#pragma unroll
    for (int r = 0; r < 16; ++r) {
        int k = (lane << 4) | r;
        int par = (__popc(k & (k >> 1)) + ((k & (k >> 9)) & 1)) & 1;
        xm[r] = par ? 0x80008000u : 0u;
        zmask |= (unsigned)(__popc(k) & 1) << r;
    }

    float xr[NQ];
#pragma unroll
    for (int q = 0; q < NQ; ++q) xr[q] = x[b * NQ + q];

    // 6 layers; wire q hits bit 9-q. Layer 0: en=0 -> sincos(0)=(0,1) -> W=V0.
    // CZ after every layer except the last (diag(+-1) is a no-op before |amp|^2).
#pragma clang loop unroll(disable)
    for (int l = 0; l <= NL; ++l) {
        const float* gl = gmf + l * NQ * 8;
        const float* lm = lam + (l > 0 ? (l - 1) * NQ : 0);
        const float en = (l > 0) ? 0.5f : 0.0f;
        float cc[NQ], ss[NQ];
#pragma unroll
        for (int q = 0; q < NQ; ++q)
            __sincosf(en * xr[q] * lm[q], &ss[q], &cc[q]);
        GATE(0, 9) GATE(1, 8) GATE(2, 7) GATE(3, 6) GATE(4, 5)
        GATE(5, 4) GATE(6, 3) GATE(7, 2) GATE(8, 1) GATE(9, 0)
        if (l != NL) {
#pragma unroll
            for (int r = 0; r < 16; ++r) a[r] = u2h(h2u(a[r]) ^ xm[r]);
        }
    }

    // <Z^n> = sum |amp|^2 * (-1)^popcount(k)  (dot2 of sign-flipped copy with itself)
    float ez = 0.f;
#pragma unroll
    for (int r = 0; r < 16; ++r) {
        unsigned zx = ((zmask >> r) & 1u) ? 0x80008000u : 0u;
        ez = fdot2(u2h(h2u(a[r]) ^ zx), a[r], ez);
    }
    ez += lane_xor_f<1>(ez, lane);
    ez += lane_xor_f<2>(ez, lane);
    ez += lane_xor_f<4>(ez, lane);
    ez += lane_xor_f<8>(ez, lane);
    ez += lane_xor_f<16>(ez, lane);
    ez += lane_xor_f<32>(ez, lane);

    if (lane == 0) {
        float l0 = ez * w[0], l1 = ez * w[1];   // BETA = 1
        float m = fmaxf(l0, l1);
        float e0 = __expf(l0 - m), e1 = __expf(l1 - m);
        float inv = 1.f / (e0 + e1);
        out[2 * b + 0] = e0 * inv;
        out[2 * b + 1] = e1 * inv;
    }
}

extern "C" void kernel_launch(void* const* d_in, const int* in_sizes, int n_in,
                              void* d_out, int out_size, void* d_ws, size_t ws_size,
                              hipStream_t stream) {
    const float* x     = (const float*)d_in[0];
    const float* theta = (const float*)d_in[1];
    const float* lam   = (const float*)d_in[2];
    const float* w     = (const float*)d_in[3];
    float* out = (float*)d_out;
    float* gmf = (float*)d_ws;                 // 60 gates * 8 f32 = 1920 B

    const int B = in_sizes[0] / NQ;            // 2048
    hipLaunchKernelGGL(pqc_setup,  dim3(1), dim3(64), 0, stream, theta, gmf);
    hipLaunchKernelGGL(pqc_kernel, dim3(B), dim3(64), 0, stream,
                       x, lam, w, gmf, out, B);
}